// Round 6
// baseline (215.623 us; speedup 1.0000x reference)
//
#include <hip/hip_runtime.h>

#define US unsigned short
#define UC unsigned char

typedef __bf16 bf16x8 __attribute__((ext_vector_type(8)));
typedef float f32x4 __attribute__((ext_vector_type(4)));
typedef unsigned int u32x4 __attribute__((ext_vector_type(4)));
typedef unsigned short u16x4 __attribute__((ext_vector_type(4)));
typedef unsigned int uint2v __attribute__((ext_vector_type(2)));

// 0.125 (softmax 1/sqrt(D)) * log2(e): folded into W'q and b'q -> P = exp2(s).
#define ALPHA_Q 0.180336880111f

#if __has_builtin(__builtin_amdgcn_exp2f)
#define EXP2F(x) __builtin_amdgcn_exp2f(x)
#else
#define EXP2F(x) __expf(0.69314718f * (x))
#endif

static __device__ __forceinline__ US f2bf(float f) {  // RTNE
    union { float f; unsigned u; } v; v.f = f;
    unsigned r = v.u + 0x7fffu + ((v.u >> 16) & 1u);
    return (US)(r >> 16);
}
static __device__ __forceinline__ float bf2f(US h) {
    union { unsigned u; float f; } v; v.u = ((unsigned)h) << 16;
    return v.f;
}
static __device__ __forceinline__ f32x4 mfma16(bf16x8 a, bf16x8 b, f32x4 c) {
    return __builtin_amdgcn_mfma_f32_16x16x32_bf16(a, b, c, 0, 0, 0);
}
static __device__ __forceinline__ f32x4 mfma_fp8(long long a, long long b, f32x4 c) {
    return __builtin_amdgcn_mfma_f32_16x16x32_fp8_fp8(a, b, c, 0, 0, 0);
}
// async global->LDS, 16B/lane; LDS dest = base + lane*16 (wave-uniform base)
static __device__ __forceinline__ void gload16(const US* g, US* l) {
    __builtin_amdgcn_global_load_lds(
        (const __attribute__((address_space(1))) void*)g,
        (__attribute__((address_space(3))) void*)l, 16, 0, 0);
}
static __device__ __forceinline__ void gload16b(const UC* g, UC* l) {
    __builtin_amdgcn_global_load_lds(
        (const __attribute__((address_space(1))) void*)g,
        (__attribute__((address_space(3))) void*)l, 16, 0, 0);
}
static __device__ __forceinline__ void stf(float* p, float v) { *p = v; }
static __device__ __forceinline__ void stf(US* p, float v) { *p = f2bf(v); }

// ---------------------------------------------------------------------------
// Fused prep: [0,6144) f32->bf16 casts; [6144,7168) 4 transposes;
// [7168,7296) bias-GEMV partials (atomicAdd into pre-zeroed b3);
// [7296,7300) v-bias copy.
// ---------------------------------------------------------------------------
__global__ __launch_bounds__(256) void prep(
    const float* __restrict__ x, US* __restrict__ xb,
    const float* __restrict__ qkvw, US* __restrict__ wv,
    const float* __restrict__ outw, US* __restrict__ wo,
    const float* __restrict__ Rm, US* __restrict__ rt,
    const float* __restrict__ Em, US* __restrict__ et,
    US* __restrict__ wqT, US* __restrict__ wkT,
    const float* __restrict__ qkvb, float* __restrict__ b3)
{
    __shared__ float t[64][65];
    const int bx = blockIdx.x;
    if (bx < 6144) {            // bulk casts: x (4096 blks), Wv (1024), Wo (1024)
        int i = bx * 256 + threadIdx.x;
        const float* s; US* d; int j;
        if (i < 1048576) { s = x; d = xb; j = i; }
        else if (i < 1310720) { s = qkvw + (size_t)2048 * 1024; d = wv; j = i - 1048576; }
        else { s = outw; d = wo; j = i - 1310720; }
        f32x4 v = ((const f32x4*)s)[j];
        u16x4 o;
        o.x = f2bf(v.x); o.y = f2bf(v.y); o.z = f2bf(v.z); o.w = f2bf(v.w);
        ((u16x4*)d)[j] = o;
    } else if (bx < 7168) {     // 4 x 1024x1024 fp32->bf16 transposes
        int r = bx - 6144;
        int z = r >> 8, xy = r & 255, tbx = xy & 15, tby = xy >> 4;
        const float* ip; US* op;
        switch (z) {
            case 0: ip = Rm; op = rt; break;
            case 1: ip = Em; op = et; break;
            case 2: ip = qkvw; op = wqT; break;
            default: ip = qkvw + (size_t)1024 * 1024; op = wkT; break;
        }
        int bc = tbx * 64, br = tby * 64;
        int lx = threadIdx.x & 63, y4 = threadIdx.x >> 6;
#pragma unroll
        for (int i = 0; i < 16; ++i) {
            int rr = i * 4 + y4;
            t[rr][lx] = ip[(size_t)(br + rr) * 1024 + bc + lx];
        }
        __syncthreads();
#pragma unroll
        for (int i = 0; i < 16; ++i) {
            int c = i * 4 + y4;
            op[(size_t)(bc + c) * 1024 + br + lx] = f2bf(t[lx][c]);
        }
    } else if (bx < 7296) {     // bias GEMV partials: 32 n-chunks x 4 j-chunks
        float (*red)[64] = (float(*)[64])t;
        const int bb = bx - 7168;
        const int tid = threadIdx.x, wave = tid >> 6, lane = tid & 63;
        const int nc = bb & 31, jc = bb >> 5;
        const int n0 = nc * 64, n = n0 + lane;
        const float* M = (n0 < 1024) ? Rm : Em;
        const float* bv = qkvb + ((n0 < 1024) ? 0 : 1024);
        const int nn = (n0 < 1024) ? n : n - 1024;
        float s = 0.f;
        const int j0 = jc * 256 + wave * 64;
#pragma unroll 8
        for (int j = 0; j < 64; ++j)
            s += bv[j0 + j] * M[(size_t)(j0 + j) * 1024 + nn];
        red[wave][lane] = s;
        __syncthreads();
        if (wave == 0) {
            float tt = red[0][lane] + red[1][lane] + red[2][lane] + red[3][lane];
            atomicAdd(&b3[n], (n0 < 1024) ? tt * ALPHA_Q : tt);
        }
    } else {                    // v-bias copy
        int i = (bx - 7296) * 256 + threadIdx.x;
        b3[2048 + i] = qkvb[2048 + i];
    }
}

// ---------------------------------------------------------------------------
// NT GEMM, 64x128 tile, BK=64 (halved barrier count): C = A.B^T (+bias)
// (+resid). 128B LDS rows with XOR granule swizzle (conflict-free b128).
// Grid (M/64, N/128); 4 waves; wave tile 32x64.
// ---------------------------------------------------------------------------
template <typename TO>
__global__ __launch_bounds__(256) void gemm_nt64(
    const US* __restrict__ A, const US* __restrict__ Bm,
    TO* __restrict__ C, const float* __restrict__ bias,
    const float* __restrict__ resid,
    int M, int N, int K, int lda, int ldb, int ldc)
{
    __shared__ __align__(16) US sA[64 * 64];    //  8 KB
    __shared__ __align__(16) US sB[128 * 64];   // 16 KB
    const int tid = threadIdx.x;
    const int wave = tid >> 6, lane = tid & 63;
    const int r16 = lane & 15, q4 = lane >> 4;
    const int wm = (wave >> 1) * 32, wn = (wave & 1) * 64;
    const int c7 = r16 & 7;

    const int l8 = lane >> 3, lg = (lane & 7) ^ l8;   // XOR baked into source
    const US* aptr = A + (size_t)(blockIdx.x * 64 + wave * 16 + l8) * lda + lg * 8;
    const US* bptr = Bm + (size_t)(blockIdx.y * 128 + wave * 32 + l8) * ldb + lg * 8;

    f32x4 acc[2][4];
#pragma unroll
    for (int i = 0; i < 2; ++i)
#pragma unroll
        for (int j = 0; j < 4; ++j) acc[i][j] = (f32x4){0.f, 0.f, 0.f, 0.f};

    for (int k0 = 0; k0 < K; k0 += 64) {
        gload16(aptr + k0, sA + (wave * 16) * 64);
        gload16(aptr + (size_t)8 * lda + k0, sA + (wave * 16 + 8) * 64);
#pragma unroll
        for (int c = 0; c < 4; ++c)
            gload16(bptr + (size_t)(c * 8) * ldb + k0, sB + (wave * 32 + c * 8) * 64);
        __syncthreads();
        bf16x8 af[2][2], bfr[4][2];
#pragma unroll
        for (int i = 0; i < 2; ++i)
#pragma unroll
            for (int hf = 0; hf < 2; ++hf)
                af[i][hf] = *(const bf16x8*)&sA[(wm + i * 16 + r16) * 64 + ((hf * 4 + q4) ^ c7) * 8];
#pragma unroll
        for (int j = 0; j < 4; ++j)
#pragma unroll
            for (int hf = 0; hf < 2; ++hf)
                bfr[j][hf] = *(const bf16x8*)&sB[(wn + j * 16 + r16) * 64 + ((hf * 4 + q4) ^ c7) * 8];
#pragma unroll
        for (int i = 0; i < 2; ++i)
#pragma unroll
            for (int j = 0; j < 4; ++j) {
                acc[i][j] = mfma16(af[i][0], bfr[j][0], acc[i][j]);
                acc[i][j] = mfma16(af[i][1], bfr[j][1], acc[i][j]);
            }
        __syncthreads();
    }

#pragma unroll
    for (int j = 0; j < 4; ++j) {
        int col = blockIdx.y * 128 + wn + j * 16 + r16;
        float bv = bias ? bias[col] : 0.f;
#pragma unroll
        for (int i = 0; i < 2; ++i) {
#pragma unroll
            for (int rr = 0; rr < 4; ++rr) {
                int row = blockIdx.x * 64 + wm + i * 16 + q4 * 4 + rr;
                float v = acc[i][j][rr] + bv;
                if (resid) v += resid[(size_t)row * ldc + col];
                stf(&C[(size_t)row * ldc + col], v);
            }
        }
    }
}

// ---------------------------------------------------------------------------
// qkv GEMM, 64x128 tile, BK=64, split epilogue: cols [0,2048) -> bf16 qk;
// cols [2048,3072) -> V fp8, transposed + key-interleaved into vt. Grid (64,24).
// ---------------------------------------------------------------------------
__global__ __launch_bounds__(256) void gemm_qkv(
    const US* __restrict__ A, const US* __restrict__ Bm,
    const float* __restrict__ bias,
    US* __restrict__ qk, UC* __restrict__ vt)
{
    __shared__ __align__(16) US sA[64 * 64];
    __shared__ __align__(16) US sB[128 * 64];
    const int tid = threadIdx.x;
    const int wave = tid >> 6, lane = tid & 63;
    const int r16 = lane & 15, q4 = lane >> 4;
    const int wm = (wave >> 1) * 32, wn = (wave & 1) * 64;
    const int c7 = r16 & 7;

    const int l8 = lane >> 3, lg = (lane & 7) ^ l8;
    const US* aptr = A + (size_t)(blockIdx.x * 64 + wave * 16 + l8) * 1024 + lg * 8;
    const US* bptr = Bm + (size_t)(blockIdx.y * 128 + wave * 32 + l8) * 1024 + lg * 8;

    f32x4 acc[2][4];
#pragma unroll
    for (int i = 0; i < 2; ++i)
#pragma unroll
        for (int j = 0; j < 4; ++j) acc[i][j] = (f32x4){0.f, 0.f, 0.f, 0.f};

    for (int k0 = 0; k0 < 1024; k0 += 64) {
        gload16(aptr + k0, sA + (wave * 16) * 64);
        gload16(aptr + (size_t)8 * 1024 + k0, sA + (wave * 16 + 8) * 64);
#pragma unroll
        for (int c = 0; c < 4; ++c)
            gload16(bptr + (size_t)(c * 8) * 1024 + k0, sB + (wave * 32 + c * 8) * 64);
        __syncthreads();
        bf16x8 af[2][2], bfr[4][2];
#pragma unroll
        for (int i = 0; i < 2; ++i)
#pragma unroll
            for (int hf = 0; hf < 2; ++hf)
                af[i][hf] = *(const bf16x8*)&sA[(wm + i * 16 + r16) * 64 + ((hf * 4 + q4) ^ c7) * 8];
#pragma unroll
        for (int j = 0; j < 4; ++j)
#pragma unroll
            for (int hf = 0; hf < 2; ++hf)
                bfr[j][hf] = *(const bf16x8*)&sB[(wn + j * 16 + r16) * 64 + ((hf * 4 + q4) ^ c7) * 8];
#pragma unroll
        for (int i = 0; i < 2; ++i)
#pragma unroll
            for (int j = 0; j < 4; ++j) {
                acc[i][j] = mfma16(af[i][0], bfr[j][0], acc[i][j]);
                acc[i][j] = mfma16(af[i][1], bfr[j][1], acc[i][j]);
            }
        __syncthreads();
    }

    if (blockIdx.y < 16) {          // q' | k' -> bf16 row-major [4096][2048]
#pragma unroll
        for (int j = 0; j < 4; ++j) {
            int col = blockIdx.y * 128 + wn + j * 16 + r16;
            float bv = bias[col];
#pragma unroll
            for (int i = 0; i < 2; ++i)
#pragma unroll
                for (int rr = 0; rr < 4; ++rr) {
                    int row = blockIdx.x * 64 + wm + i * 16 + q4 * 4 + rr;
                    qk[(size_t)row * 2048 + col] = f2bf(acc[i][j][rr] + bv);
                }
        }
    } else {                        // v -> fp8, transposed + key-interleaved
#pragma unroll
        for (int j = 0; j < 4; ++j) {
            int col = blockIdx.y * 128 + wn + j * 16 + r16;
            float bv = bias[col];
            int f = col - 2048;
#pragma unroll
            for (int i = 0; i < 2; ++i) {
                int row0 = blockIdx.x * 64 + wm + i * 16 + q4 * 4;
                int b = row0 >> 11, s0 = row0 & 2047;
                int k = s0 & 63;
                int p = (s0 & ~63) | ((k & 24) << 1) | ((k & 32) >> 2) | (k & 7);
                int dw = __builtin_amdgcn_cvt_pk_fp8_f32(
                    acc[i][j][0] + bv, acc[i][j][1] + bv, 0, false);
                dw = __builtin_amdgcn_cvt_pk_fp8_f32(
                    acc[i][j][2] + bv, acc[i][j][3] + bv, dw, true);
                *(unsigned int*)&vt[((size_t)(b * 1024 + f)) * 2048 + p] = (unsigned)dw;
            }
        }
    }
}

// ---------------------------------------------------------------------------
// Weight-fold GEMMs, 64x64 tiles, BK=64 (nt64-class staging + swizzle, halved
// barriers, 8 MFMA/wave/K-step). Both folds in one launch (z: 0=q, 1=k).
// ---------------------------------------------------------------------------
__global__ __launch_bounds__(256) void gemm_fold(
    const US* __restrict__ rt, const US* __restrict__ wqT,
    const US* __restrict__ et, const US* __restrict__ wkT,
    US* __restrict__ comb)
{
    __shared__ __align__(16) US sA[64 * 64];
    __shared__ __align__(16) US sB[64 * 64];
    const US* A; const US* Bm; US* C; float alpha;
    if (blockIdx.z == 0) { A = rt; Bm = wqT; C = comb; alpha = ALPHA_Q; }
    else { A = et; Bm = wkT; C = comb + (size_t)1024 * 1024; alpha = 1.0f; }

    const int tid = threadIdx.x;
    const int wave = tid >> 6, lane = tid & 63;
    const int r16 = lane & 15, q4 = lane >> 4;
    const int wm = (wave >> 1) * 32, wn = (wave & 1) * 32;
    const int c7 = r16 & 7;

    const int l8 = lane >> 3, lg = (lane & 7) ^ l8;
    const US* aptr = A + (size_t)(blockIdx.x * 64 + wave * 16 + l8) * 1024 + lg * 8;
    const US* bptr = Bm + (size_t)(blockIdx.y * 64 + wave * 16 + l8) * 1024 + lg * 8;

    f32x4 acc[2][2];
#pragma unroll
    for (int i = 0; i < 2; ++i)
#pragma unroll
        for (int j = 0; j < 2; ++j) acc[i][j] = (f32x4){0.f, 0.f, 0.f, 0.f};

    for (int k0 = 0; k0 < 1024; k0 += 64) {
        gload16(aptr + k0, sA + (wave * 16) * 64);
        gload16(aptr + (size_t)8 * 1024 + k0, sA + (wave * 16 + 8) * 64);
        gload16(bptr + k0, sB + (wave * 16) * 64);
        gload16(bptr + (size_t)8 * 1024 + k0, sB + (wave * 16 + 8) * 64);
        __syncthreads();
        bf16x8 af[2][2], bfr[2][2];
#pragma unroll
        for (int i = 0; i < 2; ++i)
#pragma unroll
            for (int hf = 0; hf < 2; ++hf)
                af[i][hf] = *(const bf16x8*)&sA[(wm + i * 16 + r16) * 64 + ((hf * 4 + q4) ^ c7) * 8];
#pragma unroll
        for (int j = 0; j < 2; ++j)
#pragma unroll
            for (int hf = 0; hf < 2; ++hf)
                bfr[j][hf] = *(const bf16x8*)&sB[(wn + j * 16 + r16) * 64 + ((hf * 4 + q4) ^ c7) * 8];
#pragma unroll
        for (int i = 0; i < 2; ++i)
#pragma unroll
            for (int j = 0; j < 2; ++j) {
                acc[i][j] = mfma16(af[i][0], bfr[j][0], acc[i][j]);
                acc[i][j] = mfma16(af[i][1], bfr[j][1], acc[i][j]);
            }
        __syncthreads();
    }

#pragma unroll
    for (int j = 0; j < 2; ++j) {
        int col = blockIdx.y * 64 + wn + j * 16 + r16;
#pragma unroll
        for (int i = 0; i < 2; ++i)
#pragma unroll
            for (int rr = 0; rr < 4; ++rr) {
                int row = blockIdx.x * 64 + wm + i * 16 + q4 * 4 + rr;
                C[(size_t)row * 1024 + col] = f2bf(acc[i][j][rr] * alpha);
            }
    }
}

// ---------------------------------------------------------------------------
// Flash attention, wave-private-q, SPLIT-S (2 splits x 1024 keys). This
// softmax has no running max (P = exp2(s), l = sum p) so the key loop is
// separable: block (pair, qc, sp) processes keys [sp*1024, sp*1024+1024) and
// writes UNNORMALIZED partial O (fp16) + partial l (f32); a combine kernel
// normalizes. Grid 2048 doubles resident waves/CU (TLP) and halves each
// block's serial chain (16 iters). Structure per iteration = R5 (wave-private
// q-rows, private P scratch, one K/V-recycle barrier).
// ---------------------------------------------------------------------------
__global__ __launch_bounds__(256) void attn_kernel(
    const US* __restrict__ qk, const UC* __restrict__ vt,
    _Float16* __restrict__ po, float* __restrict__ pl)
{
    __shared__ __align__(16) US sK[2 * 64 * 64];   // bf16 [buf][key][d]  16 KB
    __shared__ __align__(16) UC sV[2 * 64 * 64];   // fp8  [buf][d][key-ilv] 8 KB
    __shared__ __align__(16) UC sPw[4 * 16 * 72];  // fp8 per-wave [q][key] 4.5 KB
    const int tid = threadIdx.x;
    const int wave = tid >> 6, lane = tid & 63;
    const int r16 = lane & 15, q4 = lane >> 4;
    const int bid = blockIdx.x;                    // 2048 blocks
    const int sp = bid & 1;                        // key-split 0/1
    const int bid2 = bid >> 1;
    const int pair = (bid2 & 7) * 4 + ((bid2 >> 3) & 3);
    const int qc = bid2 >> 5;                      // 0..31
    const int h = pair & 15, b = pair >> 4;
    const int qrow0 = qc * 64;
    const int c7 = r16 & 7;
    const int kb0 = sp * 1024;                     // key base for this split
    const long long ones8 = 0x3838383838383838LL; // 1.0 in e4m3, x8

    // Q B-frags for THIS wave's 16 q-rows only (8 VGPR)
    const US* qbase = qk + ((size_t)(b * 2048 + qrow0 + wave * 16 + r16)) * 2048 + h * 64;
    const bf16x8 qf0 = *(const bf16x8*)(qbase + q4 * 8);
    const bf16x8 qf1 = *(const bf16x8*)(qbase + 32 + q4 * 8);

    f32x4 o[4];          // O^T: [d = dt*16 + q4*4+rr][q = r16]
    f32x4 lC;            // denominator: lC[*] = l(q = r16)
#pragma unroll
    for (int dt = 0; dt < 4; ++dt) o[dt] = (f32x4){0.f, 0.f, 0.f, 0.f};
    lC = (f32x4){0.f, 0.f, 0.f, 0.f};

    // staging lane constants (XOR granule swizzle baked into source address)
    const int l8 = lane >> 3;
    const US* kg = qk + ((size_t)(b * 2048 + wave * 16 + l8)) * 2048 + 1024 + h * 64
                 + ((lane & 7) ^ l8) * 8;
    const int r4 = lane >> 2;
    const UC* vg = vt + ((size_t)((b * 16 + h) * 64 + wave * 16 + r4)) * 2048
                 + ((lane & 3) ^ (r4 & 3)) * 16;

    UC* Pw = sPw + wave * (16 * 72);
    UC* pwr = Pw + r16 * 72 + q4 * 4;              // +kt*16 per write
    const UC* prd = Pw + r16 * 72 + q4 * 8;        // khalf0; +32 for khalf1

#define STAGE(kc, buf) do {                                                    \
        US* dK = sK + (buf) * 4096 + (wave * 16) * 64;                         \
        UC* dV = sV + (buf) * 4096 + (wave * 16) * 64;                         \
        gload16(kg + (size_t)(kc) * 2048, dK);                                 \
        gload16(kg + (size_t)((kc) + 8) * 2048, dK + 8 * 64);                  \
        gload16b(vg + (kc), dV);                                               \
    } while (0)

    STAGE(kb0, 0);
    __syncthreads();                 // K(0)/V(0) resident
    for (int it = 0; it < 16; ++it) {
        const int buf = it & 1;
        if (it < 15) STAGE(kb0 + (it + 1) * 64, buf ^ 1);  // prefetch
        const US* K0 = sK + buf * 4096;
        const UC* V0 = sV + buf * 4096;

        // S^T for this wave's q-rows over all 64 keys; P -> private LDS
#pragma unroll
        for (int kt = 0; kt < 4; ++kt) {
            bf16x8 kf0 = *(const bf16x8*)&K0[(kt * 16 + r16) * 64 + ((0 + q4) ^ c7) * 8];
            bf16x8 kf1 = *(const bf16x8*)&K0[(kt * 16 + r16) * 64 + ((4 + q4) ^ c7) * 8];
            f32x4 st = mfma16(kf0, qf0, (f32x4){0.f, 0.f, 0.f, 0.f});
            st = mfma16(kf1, qf1, st);
            float p0 = EXP2F(st[0]), p1 = EXP2F(st[1]);
            float p2 = EXP2F(st[2]), p3 = EXP2F(st[3]);
            int dw = __builtin_amdgcn_cvt_pk_fp8_f32(p0, p1, 0, false);
            dw = __builtin_amdgcn_cvt_pk_fp8_f32(p2, p3, dw, true);
            *(unsigned int*)(pwr + kt * 16) = (unsigned)dw;   // P[q=r16][kt*16+q4*4..+3]
        }

        // V^T A-frags for all 4 d-tiles (independent of P)
        u32x4 vv0 = *(const u32x4*)&V0[(0 * 16 + r16) * 64 + (q4 ^ (r16 & 3)) * 16];
        u32x4 vv1 = *(const u32x4*)&V0[(1 * 16 + r16) * 64 + (q4 ^ (r16 & 3)) * 16];
        u32x4 vv2 = *(const u32x4*)&V0[(2 * 16 + r16) * 64 + (q4 ^ (r16 & 3)) * 16];
        u32x4 vv3 = *(const u32x4*)&V0[(3 * 16 + r16) * 64 + (q4 ^ (r16 & 3)) * 16];

        // wave-local ordering: P writes complete before P reads (rule #18)
        asm volatile("s_waitcnt lgkmcnt(0)" ::: "memory");
        __builtin_amdgcn_sched_barrier(0);

        long long pb0 = *(const long long*)(prd);        // P[q=r16][k 8q4..+7]
        long long pb1 = *(const long long*)(prd + 32);   // P[q=r16][k 32+8q4..+7]

#define PVD(vvr, dt) do {                                                      \
        long long vf0, vf1;                                                    \
        { uint2v t0 = {(vvr).x, (vvr).y}; vf0 = *(long long*)&t0; }            \
        { uint2v t1 = {(vvr).z, (vvr).w}; vf1 = *(long long*)&t1; }            \
        o[dt] = mfma_fp8(vf0, pb0, o[dt]);                                     \
        o[dt] = mfma_fp8(vf1, pb1, o[dt]);                                     \
    } while (0)
        PVD(vv0, 0); PVD(vv1, 1); PVD(vv2, 2); PVD(vv3, 3);
#undef PVD
        lC = mfma_fp8(ones8, pb0, lC);
        lC = mfma_fp8(ones8, pb1, lC);

        __syncthreads();             // recycle K/V buf; drains prefetch too
    }
#undef STAGE

    // epilogue: unnormalized partials. lC[0] = l(q=r16) on every lane.
    const size_t row = (size_t)(b * 2048 + qrow0 + wave * 16 + r16);
    if (q4 == 0) pl[(size_t)sp * 4096 + row] = lC[0];
    _Float16* pob = po + ((size_t)sp * 4096 + row) * 1024 + h * 64;
#pragma unroll
    for (int dt = 0; dt < 4; ++dt) {
        union { _Float16 h4[4]; uint2v u; } pk_;
        pk_.h4[0] = (_Float16)o[dt][0];
        pk_.h4[1] = (_Float16)o[dt][1];
        pk_.h4[2] = (_Float16)o[dt][2];
        pk_.h4[3] = (_Float16)o[dt][3];
        *(uint2v*)&pob[dt * 16 + q4 * 4] = pk_.u;
    }
}

// ---------------------------------------------------------------------------
// Split-combine: ao[row][c] = bf16( (po0+po1)[row][c] / (l0+l1)[row] ).
// Grid 4096 (one row per block), 256 threads x 4 fp16.
// ---------------------------------------------------------------------------
__global__ __launch_bounds__(256) void combine(
    const _Float16* __restrict__ po, const float* __restrict__ pl,
    US* __restrict__ ao)
{
    const int row = blockIdx.x;
    const float inv = 1.0f / (pl[row] + pl[4096 + row]);
    const int c = threadIdx.x * 4;
    union { uint2v u; _Float16 h4[4]; } a, bq;
    a.u  = *(const uint2v*)&po[(size_t)row * 1024 + c];
    bq.u = *(const uint2v*)&po[((size_t)4096 + row) * 1024 + c];
    uint2v w;
    US w0 = f2bf(((float)a.h4[0] + (float)bq.h4[0]) * inv);
    US w1 = f2bf(((float)a.h4[1] + (float)bq.h4[1]) * inv);
    US w2 = f2bf(((float)a.h4[2] + (float)bq.h4[2]) * inv);
    US w3 = f2bf(((float)a.h4[3] + (float)bq.h4[3]) * inv);
    w.x = (unsigned)w0 | ((unsigned)w1 << 16);
    w.y = (unsigned)w2 | ((unsigned)w3 << 16);
    *(uint2v*)&ao[(size_t)row * 1024 + c] = w;
}

// ---------------------------------------------------------------------------
// B=2, S=2048, E=1024, H=16, D=64. Inputs fp32, output fp32. 6 kernels.
// ---------------------------------------------------------------------------
extern "C" void kernel_launch(void* const* d_in, const int* in_sizes, int n_in,
                              void* d_out, int out_size, void* d_ws, size_t ws_size,
                              hipStream_t stream)
{
    const float* x    = (const float*)d_in[0];
    const float* Rm   = (const float*)d_in[1];
    const float* Em   = (const float*)d_in[2];
    const float* qkvw = (const float*)d_in[3];
    const float* qkvb = (const float*)d_in[4];
    const float* outw = (const float*)d_in[5];
    const float* outb = (const float*)d_in[6];
    float* outp = (float*)d_out;

    US* ws    = (US*)d_ws;
    US* xb    = ws;
    US* rt    = xb   + (size_t)4096 * 1024;
    US* et    = rt   + (size_t)1024 * 1024;
    US* wqT   = et   + (size_t)1024 * 1024;
    US* wkT   = wqT  + (size_t)1024 * 1024;
    US* wo    = wkT  + (size_t)1024 * 1024;
    US* comb  = wo   + (size_t)1024 * 1024;   // 3072 x 1024 fused weight
    US* qkvq  = comb + (size_t)3072 * 1024;   // 4096 x 2048: q' | k' (bf16)
    US* ao    = qkvq + (size_t)4096 * 2048;
    UC* vt    = (UC*)(ao + (size_t)4096 * 1024);   // fp8 [b][feat][s-ilv], 4 MB
    float* b3 = (float*)(vt + (size_t)2048 * 2048);
    _Float16* po = (_Float16*)(b3 + 4096);          // 2 x 4096 x 1024 fp16, 16 MB
    float* pl = (float*)(po + (size_t)2 * 4096 * 1024);  // 2 x 4096 f32

    // zero the accumulated bias region (atomicAdd targets)
    hipMemsetAsync(b3, 0, 2048 * sizeof(float), stream);
    // casts + 4 transposes + bias-GEMV partials + v-bias in one launch
    prep<<<dim3(7300), dim3(256), 0, stream>>>(
        x, xb, qkvw, comb + (size_t)2048 * 1024, outw, wo,
        Rm, rt, Em, et, wqT, wkT, qkvb, b3);
    // comb_q = ALPHA_Q * R^T Wq ; comb_k = E^T Wk  (BK=64)
    gemm_fold<<<dim3(16, 16, 2), dim3(256), 0, stream>>>(rt, wqT, et, wkT, comb);
    // qkv: q'|k' -> qkvq (bf16), v -> vt (fp8, transposed+interleaved)
    gemm_qkv<<<dim3(64, 24), dim3(256), 0, stream>>>(xb, comb, b3, qkvq, vt);
    // attention: split-S partials (2 x 1024 keys), then normalize-combine
    attn_kernel<<<dim3(2048), dim3(256), 0, stream>>>(qkvq, vt, po, pl);
    combine<<<dim3(4096), dim3(256), 0, stream>>>(po, pl, ao);
    // out = ao @ out_w^T + out_b + x
    gemm_nt64<float><<<dim3(64, 8), dim3(256), 0, stream>>>(ao, wo, outp, outb, x,
                                                            4096, 1024, 1024, 1024, 1024, 1024);
}